// Round 3
// baseline (2620.666 us; speedup 1.0000x reference)
//
#include <hip/hip_runtime.h>

// GCN: 4 layers (64->64->64->64->16), N=100k nodes, E=1.6M edges (+ self loops).
// out[i] = dis[i] * ( sum_{src->i} t[src] + t[i] ) + b,  t = dis * (h @ W)
// Round 3: coarse dst-bucket binning (128 nodes/bucket) + LDS-accumulator
// push-gather. Removes per-node CSR fill (was 105MB write-allocate traffic).

#define BKT_SHIFT 7
#define BKT_NODES 128           // nodes per bucket
#define NBMAX 800               // max buckets (n <= 102400)
#define EPT 16                  // edges per thread in binning

// ---------------- degree / norm ----------------

__global__ void k_hist(const int* __restrict__ dst, int e, int* __restrict__ cnt) {
    int i = blockIdx.x * blockDim.x + threadIdx.x;
    if (i < e) atomicAdd(&cnt[dst[i]], 1);
}

__global__ void k_dis(const int* __restrict__ cnt, float* __restrict__ dis, int n) {
    int i = blockIdx.x * blockDim.x + threadIdx.x;
    if (i < n) dis[i] = rsqrtf((float)(cnt[i] + 1));   // +1 self loop
}

// bucket_cnt[b] = sum of cnt over the bucket's 128 nodes. One wave per bucket.
__global__ void k_bsum(const int* __restrict__ cnt, int* __restrict__ bcnt, int n) {
    int b = blockIdx.x, lane = threadIdx.x;
    int base = b * BKT_NODES;
    int v = 0;
    int i0 = base + lane;      if (i0 < n) v += cnt[i0];
    int i1 = base + 64 + lane; if (i1 < n) v += cnt[i1];
    for (int off = 32; off; off >>= 1) v += __shfl_down(v, off);
    if (lane == 0) bcnt[b] = v;
}

// single-block exclusive scan of nb (<=1024) bucket counts -> bkt_off, gcursor
__global__ void k_bscan(const int* __restrict__ bcnt, int* __restrict__ bkt_off,
                        int* __restrict__ gcursor, int nb, int e) {
    __shared__ int lds[256];
    int tdx = threadIdx.x;
    int v[4], s = 0;
#pragma unroll
    for (int k = 0; k < 4; ++k) { int idx = tdx * 4 + k; v[k] = (idx < nb) ? bcnt[idx] : 0; s += v[k]; }
    lds[tdx] = s;
    __syncthreads();
    for (int off = 1; off < 256; off <<= 1) {
        int x = (tdx >= off) ? lds[tdx - off] : 0;
        __syncthreads();
        if (tdx >= off) lds[tdx] += x;
        __syncthreads();
    }
    int run = lds[tdx] - s;
#pragma unroll
    for (int k = 0; k < 4; ++k) {
        int idx = tdx * 4 + k;
        if (idx < nb) { bkt_off[idx] = run; gcursor[idx] = run; }
        run += v[k];
    }
    if (tdx == 0) bkt_off[nb] = e;
}

// bin edges into buckets: bkt_edges[p] = (src<<7) | (dst & 127)
__global__ __launch_bounds__(256) void k_binA(const int* __restrict__ src,
                                              const int* __restrict__ dst, int e, int nb,
                                              int* __restrict__ gcursor,
                                              unsigned* __restrict__ bkt_edges) {
    __shared__ int lcnt[NBMAX];
    __shared__ int lbase[NBMAX];
    int tdx = threadIdx.x;
    for (int i = tdx; i < nb; i += 256) lcnt[i] = 0;
    __syncthreads();
    int base = blockIdx.x * (256 * EPT);
    unsigned val[EPT];
    int bkt[EPT];
#pragma unroll
    for (int k = 0; k < EPT; ++k) {
        int i = base + k * 256 + tdx;
        if (i < e) {
            int s_ = src[i], d_ = dst[i];
            val[k] = ((unsigned)s_ << BKT_SHIFT) | (unsigned)(d_ & (BKT_NODES - 1));
            bkt[k] = d_ >> BKT_SHIFT;
            atomicAdd(&lcnt[bkt[k]], 1);
        } else bkt[k] = -1;
    }
    __syncthreads();
    for (int b = tdx; b < nb; b += 256) {
        int c = lcnt[b];
        lbase[b] = c ? atomicAdd(&gcursor[b], c) : 0;
        lcnt[b] = 0;
    }
    __syncthreads();
#pragma unroll
    for (int k = 0; k < EPT; ++k) {
        if (bkt[k] >= 0) {
            int o = atomicAdd(&lcnt[bkt[k]], 1);
            bkt_edges[lbase[bkt[k]] + o] = val[k];
        }
    }
}

// ---------------- matmul (t = dis * (x @ W)) ----------------

__global__ void k_matmul64(const float* __restrict__ x, const float* __restrict__ W,
                           const float* __restrict__ dis, float* __restrict__ t, int n) {
    __shared__ float Ws[64 * 64];
    for (int i = threadIdx.x; i < 64 * 64; i += blockDim.x) Ws[i] = W[i];
    __syncthreads();
    int lane = threadIdx.x & 63;
    int wid  = (blockIdx.x * blockDim.x + threadIdx.x) >> 6;
    int nw   = (gridDim.x * blockDim.x) >> 6;
    for (int row = wid; row < n; row += nw) {
        float xv  = x[(size_t)row * 64 + lane];
        float acc = 0.f;
#pragma unroll
        for (int k = 0; k < 64; ++k) {
            float xk = __shfl(xv, k);
            acc = fmaf(xk, Ws[k * 64 + lane], acc);
        }
        t[(size_t)row * 64 + lane] = acc * dis[row];
    }
}

__global__ void k_matmul16(const float* __restrict__ x, const float* __restrict__ W,
                           const float* __restrict__ dis, float* __restrict__ t, int n) {
    __shared__ float Ws[64 * 16];
    for (int i = threadIdx.x; i < 64 * 16; i += blockDim.x) Ws[i] = W[i];
    __syncthreads();
    int stride = gridDim.x * blockDim.x;
    for (int idx = blockIdx.x * blockDim.x + threadIdx.x; idx < n * 16; idx += stride) {
        int row = idx >> 4, f = idx & 15;
        const float* xr = x + (size_t)row * 64;
        float acc = 0.f;
#pragma unroll
        for (int k = 0; k < 64; ++k) acc = fmaf(xr[k], Ws[k * 16 + f], acc);
        t[idx] = acc * dis[row];
    }
}

// ---------------- bucket gather (LDS accumulator, fused finalize) ----------------
// block = 1 bucket (128 nodes), 256 threads. Edge: (src<<7)|nodelocal.
// Per edge: broadcast edge-word load, 256B coalesced t-row read, 1 ds_add wave-op.
__global__ __launch_bounds__(256) void k_bgather64(
    const int* __restrict__ bkt_off, const unsigned* __restrict__ bkt_edges,
    const float* __restrict__ t, const float* __restrict__ dis,
    const float* __restrict__ b, float* __restrict__ h, int n, int relu) {
    __shared__ float acc[BKT_NODES * 64];
    int tdx  = threadIdx.x;
    int nb0  = blockIdx.x * BKT_NODES;
    // init with self-loop rows
    for (int i = tdx; i < BKT_NODES * 64; i += 256) {
        int node = nb0 + (i >> 6);
        acc[i] = (node < n) ? t[(size_t)node * 64 + (i & 63)] : 0.f;
    }
    __syncthreads();
    int beg = bkt_off[blockIdx.x], end = bkt_off[blockIdx.x + 1];
    int cnt = end - beg;
    int wave = tdx >> 6, lane = tdx & 63;
    int chunk = (cnt + 3) >> 2;
    int jb = beg + wave * chunk;
    int je = jb + chunk; if (je > end) je = end; if (jb > end) jb = end;
    int j = jb;
    for (; j + 8 <= je; j += 8) {
        unsigned e0 = bkt_edges[j+0], e1 = bkt_edges[j+1], e2 = bkt_edges[j+2], e3 = bkt_edges[j+3];
        unsigned e4 = bkt_edges[j+4], e5 = bkt_edges[j+5], e6 = bkt_edges[j+6], e7 = bkt_edges[j+7];
        float v0 = t[(size_t)(e0 >> 7) * 64 + lane];
        float v1 = t[(size_t)(e1 >> 7) * 64 + lane];
        float v2 = t[(size_t)(e2 >> 7) * 64 + lane];
        float v3 = t[(size_t)(e3 >> 7) * 64 + lane];
        float v4 = t[(size_t)(e4 >> 7) * 64 + lane];
        float v5 = t[(size_t)(e5 >> 7) * 64 + lane];
        float v6 = t[(size_t)(e6 >> 7) * 64 + lane];
        float v7 = t[(size_t)(e7 >> 7) * 64 + lane];
        atomicAdd(&acc[(e0 & 127) * 64 + lane], v0);
        atomicAdd(&acc[(e1 & 127) * 64 + lane], v1);
        atomicAdd(&acc[(e2 & 127) * 64 + lane], v2);
        atomicAdd(&acc[(e3 & 127) * 64 + lane], v3);
        atomicAdd(&acc[(e4 & 127) * 64 + lane], v4);
        atomicAdd(&acc[(e5 & 127) * 64 + lane], v5);
        atomicAdd(&acc[(e6 & 127) * 64 + lane], v6);
        atomicAdd(&acc[(e7 & 127) * 64 + lane], v7);
    }
    for (; j < je; ++j) {
        unsigned e0 = bkt_edges[j];
        atomicAdd(&acc[(e0 & 127) * 64 + lane], t[(size_t)(e0 >> 7) * 64 + lane]);
    }
    __syncthreads();
    // finalize: h = [relu]( dis * acc + b )
    for (int i = tdx; i < BKT_NODES * 64; i += 256) {
        int node = nb0 + (i >> 6), f = i & 63;
        if (node < n) {
            float v = fmaf(dis[node], acc[i], b[f]);
            if (relu) v = fmaxf(v, 0.f);
            h[(size_t)node * 64 + f] = v;
        }
    }
}

// 16-feature variant: 16 lanes per edge (4 edges per wave via lane groups).
__global__ __launch_bounds__(256) void k_bgather16(
    const int* __restrict__ bkt_off, const unsigned* __restrict__ bkt_edges,
    const float* __restrict__ t, const float* __restrict__ dis,
    const float* __restrict__ b, float* __restrict__ out, int n) {
    __shared__ float acc[BKT_NODES * 16];
    int tdx = threadIdx.x;
    int nb0 = blockIdx.x * BKT_NODES;
    for (int i = tdx; i < BKT_NODES * 16; i += 256) {
        int node = nb0 + (i >> 4);
        acc[i] = (node < n) ? t[(size_t)node * 16 + (i & 15)] : 0.f;
    }
    __syncthreads();
    int beg = bkt_off[blockIdx.x], end = bkt_off[blockIdx.x + 1];
    int cnt = end - beg;
    int gid = tdx >> 4, fl = tdx & 15;           // 16 groups of 16 lanes
    int chunk = (cnt + 15) >> 4;
    int jb = beg + gid * chunk;
    int je = jb + chunk; if (je > end) je = end; if (jb > end) jb = end;
    int j = jb;
    for (; j + 2 <= je; j += 2) {
        unsigned e0 = bkt_edges[j], e1 = bkt_edges[j + 1];
        float v0 = t[(size_t)(e0 >> 7) * 16 + fl];
        float v1 = t[(size_t)(e1 >> 7) * 16 + fl];
        atomicAdd(&acc[(e0 & 127) * 16 + fl], v0);
        atomicAdd(&acc[(e1 & 127) * 16 + fl], v1);
    }
    for (; j < je; ++j) {
        unsigned e0 = bkt_edges[j];
        atomicAdd(&acc[(e0 & 127) * 16 + fl], t[(size_t)(e0 >> 7) * 16 + fl]);
    }
    __syncthreads();
    for (int i = tdx; i < BKT_NODES * 16; i += 256) {
        int node = nb0 + (i >> 4), f = i & 15;
        if (node < n)
            out[(size_t)node * 16 + f] = fmaf(dis[node], acc[i], b[f]);
    }
}

// ---------------- launch ----------------

extern "C" void kernel_launch(void* const* d_in, const int* in_sizes, int n_in,
                              void* d_out, int out_size, void* d_ws, size_t ws_size,
                              hipStream_t stream) {
    const float* x     = (const float*)d_in[0];
    const int*   ei    = (const int*)d_in[1];
    const float* W_in  = (const float*)d_in[2];
    const float* b_in  = (const float*)d_in[3];
    const float* W_h   = (const float*)d_in[4];
    const float* b_h   = (const float*)d_in[5];
    const float* W_out = (const float*)d_in[6];
    const float* b_out = (const float*)d_in[7];

    const int n = in_sizes[0] / 64;
    const int e = in_sizes[1] / 2;
    const int* src = ei;
    const int* dst = ei + e;
    const int nb = (n + BKT_NODES - 1) / BKT_NODES;
    if (nb > NBMAX) return;   // fixed problem: n=100000 -> nb=782

    char* ws = (char*)d_ws;
    size_t off = 0;
    auto alloc = [&](size_t bytes) { void* p = ws + off; off += (bytes + 255) & ~(size_t)255; return p; };
    float*    dis       = (float*)alloc((size_t)n * 4);
    float*    t         = (float*)alloc((size_t)n * 64 * 4);
    float*    h         = (float*)alloc((size_t)n * 64 * 4);
    int*      cnt       = (int*)alloc((size_t)n * 4);
    int*      bcnt      = (int*)alloc((size_t)nb * 4);
    int*      bkt_off   = (int*)alloc(((size_t)nb + 1) * 4);
    int*      gcursor   = (int*)alloc((size_t)nb * 4);
    unsigned* bkt_edges = (unsigned*)alloc((size_t)e * 4);

    // ---- degree + binning ----
    hipMemsetAsync(cnt, 0, (size_t)n * 4, stream);
    k_hist <<<(e + 255) / 256, 256, 0, stream>>>(dst, e, cnt);
    k_dis  <<<(n + 255) / 256, 256, 0, stream>>>(cnt, dis, n);
    k_bsum <<<nb, 64, 0, stream>>>(cnt, bcnt, n);
    k_bscan<<<1, 256, 0, stream>>>(bcnt, bkt_off, gcursor, nb, e);
    k_binA <<<(e + 256 * EPT - 1) / (256 * EPT), 256, 0, stream>>>(src, dst, e, nb, gcursor, bkt_edges);

    // ---- layer 1: x -> h ----
    k_matmul64 <<<4096, 256, 0, stream>>>(x, W_in, dis, t, n);
    k_bgather64<<<nb, 256, 0, stream>>>(bkt_off, bkt_edges, t, dis, b_in, h, n, 1);

    // ---- layers 2,3: h -> h ----
    for (int l = 0; l < 2; ++l) {
        k_matmul64 <<<4096, 256, 0, stream>>>(h, W_h + (size_t)l * 64 * 64, dis, t, n);
        k_bgather64<<<nb, 256, 0, stream>>>(bkt_off, bkt_edges, t, dis,
                                            b_h + (size_t)l * 64, h, n, 1);
    }

    // ---- layer 4: h -> out (FOUT=16, no relu) ----
    k_matmul16 <<<4096, 256, 0, stream>>>(h, W_out, dis, t, n);
    k_bgather16<<<nb, 256, 0, stream>>>(bkt_off, bkt_edges, t, dis, b_out, (float*)d_out, n);
}

// Round 4
// 543.931 us; speedup vs baseline: 4.8180x; 4.8180x over previous
//
#include <hip/hip_runtime.h>

// GCN: 4 layers (64->64->64->64->16), N=100k nodes, E=1.6M edges (+ self loops).
// out[i] = dis[i] * ( sum_{src->i} t[src] + t[i] ) + b,  t = dis * (h @ W)
// Round 4: round-2 per-node CSR gather (proven, TLP-rich) + cheap CSR build:
// bucket-count -> 782-scan -> bucket-place -> per-bucket counting sort
// (replaces per-node hist + 100k scan + scattered fill that cost ~185us).

#define BKT_SHIFT 7
#define BKT_NODES 128
#define NBMAX 800               // max buckets (n <= 102400)
#define EPT 16                  // edges per thread in binning

// ---- bucket count: per-block LDS hist -> one global atomic per bucket ----
__global__ __launch_bounds__(256) void k_bcount(const int* __restrict__ dst, int e,
                                                int* __restrict__ bcnt, int nb) {
    __shared__ int l[NBMAX];
    int tdx = threadIdx.x;
    for (int i = tdx; i < nb; i += 256) l[i] = 0;
    __syncthreads();
    int base = blockIdx.x * (256 * EPT);
#pragma unroll
    for (int k = 0; k < EPT; ++k) {
        int i = base + k * 256 + tdx;
        if (i < e) atomicAdd(&l[dst[i] >> BKT_SHIFT], 1);
    }
    __syncthreads();
    for (int i = tdx; i < nb; i += 256) {
        int c = l[i];
        if (c) atomicAdd(&bcnt[i], c);
    }
}

// ---- single-block exclusive scan of nb (<=1024) bucket counts ----
__global__ void k_bscan(const int* __restrict__ bcnt, int* __restrict__ bkt_off,
                        int* __restrict__ gcursor, int nb, int e) {
    __shared__ int lds[256];
    int tdx = threadIdx.x;
    int v[4], s = 0;
#pragma unroll
    for (int k = 0; k < 4; ++k) { int idx = tdx * 4 + k; v[k] = (idx < nb) ? bcnt[idx] : 0; s += v[k]; }
    lds[tdx] = s;
    __syncthreads();
    for (int off = 1; off < 256; off <<= 1) {
        int x = (tdx >= off) ? lds[tdx - off] : 0;
        __syncthreads();
        if (tdx >= off) lds[tdx] += x;
        __syncthreads();
    }
    int run = lds[tdx] - s;
#pragma unroll
    for (int k = 0; k < 4; ++k) {
        int idx = tdx * 4 + k;
        if (idx < nb) { bkt_off[idx] = run; gcursor[idx] = run; }
        run += v[k];
    }
    if (tdx == 0) bkt_off[nb] = e;
}

// ---- place edges into buckets: bkt_edges[p] = (src<<7) | (dst & 127) ----
__global__ __launch_bounds__(256) void k_binB(const int* __restrict__ src,
                                              const int* __restrict__ dst, int e, int nb,
                                              int* __restrict__ gcursor,
                                              unsigned* __restrict__ bkt_edges) {
    __shared__ int lcnt[NBMAX];
    __shared__ int lbase[NBMAX];
    int tdx = threadIdx.x;
    for (int i = tdx; i < nb; i += 256) lcnt[i] = 0;
    __syncthreads();
    int base = blockIdx.x * (256 * EPT);
    unsigned val[EPT];
    int bkt[EPT];
#pragma unroll
    for (int k = 0; k < EPT; ++k) {
        int i = base + k * 256 + tdx;
        if (i < e) {
            int s_ = src[i], d_ = dst[i];
            val[k] = ((unsigned)s_ << BKT_SHIFT) | (unsigned)(d_ & (BKT_NODES - 1));
            bkt[k] = d_ >> BKT_SHIFT;
            atomicAdd(&lcnt[bkt[k]], 1);
        } else bkt[k] = -1;
    }
    __syncthreads();
    for (int b = tdx; b < nb; b += 256) {
        int c = lcnt[b];
        lbase[b] = c ? atomicAdd(&gcursor[b], c) : 0;
        lcnt[b] = 0;
    }
    __syncthreads();
#pragma unroll
    for (int k = 0; k < EPT; ++k) {
        if (bkt[k] >= 0) {
            int o = atomicAdd(&lcnt[bkt[k]], 1);
            bkt_edges[lbase[bkt[k]] + o] = val[k];
        }
    }
}

// ---- per-bucket counting sort -> per-node CSR + row_ptr + dis ----
// one block per bucket; writes land densely within the bucket's window.
__global__ __launch_bounds__(256) void k_bsort(
    const int* __restrict__ bkt_off, const unsigned* __restrict__ bkt_edges,
    int* __restrict__ row_ptr, int* __restrict__ csr_src, float* __restrict__ dis,
    int n, int e, int nb) {
    __shared__ int hist[BKT_NODES];
    __shared__ int sc[BKT_NODES];
    __shared__ int cur[BKT_NODES];
    int b = blockIdx.x, tdx = threadIdx.x;
    int beg = bkt_off[b], end = bkt_off[b + 1];
    if (tdx < BKT_NODES) hist[tdx] = 0;
    __syncthreads();
    for (int j = beg + tdx; j < end; j += 256)
        atomicAdd(&hist[bkt_edges[j] & (BKT_NODES - 1)], 1);
    __syncthreads();
    if (tdx < BKT_NODES) sc[tdx] = hist[tdx];
    __syncthreads();
    for (int off = 1; off < BKT_NODES; off <<= 1) {
        int v = (tdx < BKT_NODES && tdx >= off) ? sc[tdx - off] : 0;
        __syncthreads();
        if (tdx < BKT_NODES && tdx >= off) sc[tdx] += v;
        __syncthreads();
    }
    if (tdx < BKT_NODES) {
        int node = b * BKT_NODES + tdx;
        if (node < n) {
            int pos = beg + sc[tdx] - hist[tdx];   // exclusive prefix
            row_ptr[node] = pos;
            cur[tdx] = pos;
            dis[node] = rsqrtf((float)(hist[tdx] + 1));   // +1 self loop
        }
    }
    if (b == nb - 1 && tdx == 0) row_ptr[n] = e;
    __syncthreads();
    for (int j = beg + tdx; j < end; j += 256) {
        unsigned ev = bkt_edges[j];
        int p = atomicAdd(&cur[ev & (BKT_NODES - 1)], 1);
        csr_src[p] = (int)(ev >> BKT_SHIFT);
    }
}

// ---------------- matmul (t = dis * (x @ W)) ----------------

__global__ void k_matmul64(const float* __restrict__ x, const float* __restrict__ W,
                           const float* __restrict__ dis, float* __restrict__ t, int n) {
    __shared__ float Ws[64 * 64];
    for (int i = threadIdx.x; i < 64 * 64; i += blockDim.x) Ws[i] = W[i];
    __syncthreads();
    int lane = threadIdx.x & 63;
    int wid  = (blockIdx.x * blockDim.x + threadIdx.x) >> 6;
    int nw   = (gridDim.x * blockDim.x) >> 6;
    for (int row = wid; row < n; row += nw) {
        float xv  = x[(size_t)row * 64 + lane];
        float acc = 0.f;
#pragma unroll
        for (int k = 0; k < 64; ++k) {
            float xk = __shfl(xv, k);
            acc = fmaf(xk, Ws[k * 64 + lane], acc);
        }
        t[(size_t)row * 64 + lane] = acc * dis[row];
    }
}

__global__ void k_matmul16(const float* __restrict__ x, const float* __restrict__ W,
                           const float* __restrict__ dis, float* __restrict__ t, int n) {
    __shared__ float Ws[64 * 16];
    for (int i = threadIdx.x; i < 64 * 16; i += blockDim.x) Ws[i] = W[i];
    __syncthreads();
    int stride = gridDim.x * blockDim.x;
    for (int idx = blockIdx.x * blockDim.x + threadIdx.x; idx < n * 16; idx += stride) {
        int row = idx >> 4, f = idx & 15;
        const float* xr = x + (size_t)row * 64;
        float acc = 0.f;
#pragma unroll
        for (int k = 0; k < 64; ++k) acc = fmaf(xr[k], Ws[k * 16 + f], acc);
        t[idx] = acc * dis[row];
    }
}

// ---------------- gather (fused aggregate + finalize) ----------------
// one node per 16 lanes; lane holds float4. 2-edge unroll for ILP.
__global__ void k_gather64(const int* __restrict__ row_ptr, const int* __restrict__ csr_src,
                           const float* __restrict__ t, const float* __restrict__ dis,
                           const float* __restrict__ b, float* __restrict__ h, int n, int relu) {
    int tid  = blockIdx.x * blockDim.x + threadIdx.x;
    int node = tid >> 4;
    if (node >= n) return;
    int lane15  = threadIdx.x & 15;
    int grpbase = threadIdx.x & 48;
    int beg = row_ptr[node], end = row_ptr[node + 1];

    float4 acc = *(const float4*)(t + (size_t)node * 64 + lane15 * 4);   // self loop
    for (int j0 = beg; j0 < end; j0 += 16) {
        int myj = j0 + lane15;
        int sv  = (myj < end) ? csr_src[myj] : 0;
        int m   = end - j0; if (m > 16) m = 16;
        int k = 0;
        for (; k + 2 <= m; k += 2) {
            int s0 = __shfl(sv, grpbase + k);
            int s1 = __shfl(sv, grpbase + k + 1);
            const float4 v0 = *(const float4*)(t + (size_t)s0 * 64 + lane15 * 4);
            const float4 v1 = *(const float4*)(t + (size_t)s1 * 64 + lane15 * 4);
            acc.x += v0.x; acc.y += v0.y; acc.z += v0.z; acc.w += v0.w;
            acc.x += v1.x; acc.y += v1.y; acc.z += v1.z; acc.w += v1.w;
        }
        if (k < m) {
            int s0 = __shfl(sv, grpbase + k);
            const float4 v0 = *(const float4*)(t + (size_t)s0 * 64 + lane15 * 4);
            acc.x += v0.x; acc.y += v0.y; acc.z += v0.z; acc.w += v0.w;
        }
    }
    float dn = dis[node];
    const float4 bb = *(const float4*)(b + lane15 * 4);
    float4 o;
    o.x = fmaf(dn, acc.x, bb.x);
    o.y = fmaf(dn, acc.y, bb.y);
    o.z = fmaf(dn, acc.z, bb.z);
    o.w = fmaf(dn, acc.w, bb.w);
    if (relu) {
        o.x = fmaxf(o.x, 0.f); o.y = fmaxf(o.y, 0.f);
        o.z = fmaxf(o.z, 0.f); o.w = fmaxf(o.w, 0.f);
    }
    *(float4*)(h + (size_t)node * 64 + lane15 * 4) = o;
}

// one node per 4 lanes; lane holds float4 (4 of 16 features). No relu.
__global__ void k_gather16(const int* __restrict__ row_ptr, const int* __restrict__ csr_src,
                           const float* __restrict__ t, const float* __restrict__ dis,
                           const float* __restrict__ b, float* __restrict__ out, int n) {
    int tid  = blockIdx.x * blockDim.x + threadIdx.x;
    int node = tid >> 2;
    if (node >= n) return;
    int lane3   = threadIdx.x & 3;
    int grpbase = threadIdx.x & 60;
    int beg = row_ptr[node], end = row_ptr[node + 1];

    float4 acc = *(const float4*)(t + (size_t)node * 16 + lane3 * 4);    // self loop
    for (int j0 = beg; j0 < end; j0 += 4) {
        int myj = j0 + lane3;
        int sv  = (myj < end) ? csr_src[myj] : 0;
        int m   = end - j0; if (m > 4) m = 4;
        int k = 0;
        for (; k + 2 <= m; k += 2) {
            int s0 = __shfl(sv, grpbase + k);
            int s1 = __shfl(sv, grpbase + k + 1);
            const float4 v0 = *(const float4*)(t + (size_t)s0 * 16 + lane3 * 4);
            const float4 v1 = *(const float4*)(t + (size_t)s1 * 16 + lane3 * 4);
            acc.x += v0.x; acc.y += v0.y; acc.z += v0.z; acc.w += v0.w;
            acc.x += v1.x; acc.y += v1.y; acc.z += v1.z; acc.w += v1.w;
        }
        if (k < m) {
            int s0 = __shfl(sv, grpbase + k);
            const float4 v0 = *(const float4*)(t + (size_t)s0 * 16 + lane3 * 4);
            acc.x += v0.x; acc.y += v0.y; acc.z += v0.z; acc.w += v0.w;
        }
    }
    float dn = dis[node];
    const float4 bb = *(const float4*)(b + lane3 * 4);
    float4 o;
    o.x = fmaf(dn, acc.x, bb.x);
    o.y = fmaf(dn, acc.y, bb.y);
    o.z = fmaf(dn, acc.z, bb.z);
    o.w = fmaf(dn, acc.w, bb.w);
    *(float4*)(out + (size_t)node * 16 + lane3 * 4) = o;
}

// ---------------- launch ----------------

extern "C" void kernel_launch(void* const* d_in, const int* in_sizes, int n_in,
                              void* d_out, int out_size, void* d_ws, size_t ws_size,
                              hipStream_t stream) {
    const float* x     = (const float*)d_in[0];
    const int*   ei    = (const int*)d_in[1];
    const float* W_in  = (const float*)d_in[2];
    const float* b_in  = (const float*)d_in[3];
    const float* W_h   = (const float*)d_in[4];
    const float* b_h   = (const float*)d_in[5];
    const float* W_out = (const float*)d_in[6];
    const float* b_out = (const float*)d_in[7];

    const int n = in_sizes[0] / 64;
    const int e = in_sizes[1] / 2;
    const int* src = ei;
    const int* dst = ei + e;
    const int nb = (n + BKT_NODES - 1) / BKT_NODES;   // 782
    if (nb > NBMAX) return;

    char* ws = (char*)d_ws;
    size_t off = 0;
    auto alloc = [&](size_t bytes) { void* p = ws + off; off += (bytes + 255) & ~(size_t)255; return p; };
    float*    dis       = (float*)alloc((size_t)n * 4);
    float*    t         = (float*)alloc((size_t)n * 64 * 4);
    float*    h         = (float*)alloc((size_t)n * 64 * 4);
    int*      bcnt      = (int*)alloc((size_t)nb * 4);
    int*      bkt_off   = (int*)alloc(((size_t)nb + 1) * 4);
    int*      gcursor   = (int*)alloc((size_t)nb * 4);
    unsigned* bkt_edges = (unsigned*)alloc((size_t)e * 4);
    int*      row_ptr   = (int*)alloc(((size_t)n + 1) * 4);
    int*      csr_src   = (int*)alloc((size_t)e * 4);

    const int nblk_e = (e + 256 * EPT - 1) / (256 * EPT);

    // ---- CSR build (bucketed) ----
    hipMemsetAsync(bcnt, 0, (size_t)nb * 4, stream);
    k_bcount<<<nblk_e, 256, 0, stream>>>(dst, e, bcnt, nb);
    k_bscan <<<1, 256, 0, stream>>>(bcnt, bkt_off, gcursor, nb, e);
    k_binB  <<<nblk_e, 256, 0, stream>>>(src, dst, e, nb, gcursor, bkt_edges);
    k_bsort <<<nb, 256, 0, stream>>>(bkt_off, bkt_edges, row_ptr, csr_src, dis, n, e, nb);

    // ---- layer 1: x -> h ----
    k_matmul64<<<4096, 256, 0, stream>>>(x, W_in, dis, t, n);
    k_gather64<<<(n * 16 + 255) / 256, 256, 0, stream>>>(row_ptr, csr_src, t, dis, b_in, h, n, 1);

    // ---- layers 2,3: h -> h ----
    for (int l = 0; l < 2; ++l) {
        k_matmul64<<<4096, 256, 0, stream>>>(h, W_h + (size_t)l * 64 * 64, dis, t, n);
        k_gather64<<<(n * 16 + 255) / 256, 256, 0, stream>>>(row_ptr, csr_src, t, dis,
                                                             b_h + (size_t)l * 64, h, n, 1);
    }

    // ---- layer 4: h -> out (FOUT=16, no relu) ----
    k_matmul16<<<4096, 256, 0, stream>>>(h, W_out, dis, t, n);
    k_gather16<<<(n * 4 + 255) / 256, 256, 0, stream>>>(row_ptr, csr_src, t, dis, b_out,
                                                        (float*)d_out, n);
}

// Round 5
// 382.315 us; speedup vs baseline: 6.8547x; 1.4227x over previous
//
#include <hip/hip_runtime.h>

// GCN: 4 layers (64->64->64->64->16), N=100k nodes, E=1.6M edges (+ self loops).
// out[i] = dis[i] * ( sum_{src->i} t[src] + t[i] ) + b,  t = dis * (h @ W)
// Round 5: register-blocked row-per-thread matmul (64 acc VGPRs, wave-uniform
// W loads -> scalar/broadcast path, no LDS). CSR build + gather from round 4.

#define BKT_SHIFT 7
#define BKT_NODES 128
#define NBMAX 800               // max buckets (n <= 102400)
#define EPT 16                  // edges per thread in binning

// ---- bucket count: per-block LDS hist -> one global atomic per bucket ----
__global__ __launch_bounds__(256) void k_bcount(const int* __restrict__ dst, int e,
                                                int* __restrict__ bcnt, int nb) {
    __shared__ int l[NBMAX];
    int tdx = threadIdx.x;
    for (int i = tdx; i < nb; i += 256) l[i] = 0;
    __syncthreads();
    int base = blockIdx.x * (256 * EPT);
#pragma unroll
    for (int k = 0; k < EPT; ++k) {
        int i = base + k * 256 + tdx;
        if (i < e) atomicAdd(&l[dst[i] >> BKT_SHIFT], 1);
    }
    __syncthreads();
    for (int i = tdx; i < nb; i += 256) {
        int c = l[i];
        if (c) atomicAdd(&bcnt[i], c);
    }
}

// ---- single-block exclusive scan of nb (<=1024) bucket counts ----
__global__ void k_bscan(const int* __restrict__ bcnt, int* __restrict__ bkt_off,
                        int* __restrict__ gcursor, int nb, int e) {
    __shared__ int lds[256];
    int tdx = threadIdx.x;
    int v[4], s = 0;
#pragma unroll
    for (int k = 0; k < 4; ++k) { int idx = tdx * 4 + k; v[k] = (idx < nb) ? bcnt[idx] : 0; s += v[k]; }
    lds[tdx] = s;
    __syncthreads();
    for (int off = 1; off < 256; off <<= 1) {
        int x = (tdx >= off) ? lds[tdx - off] : 0;
        __syncthreads();
        if (tdx >= off) lds[tdx] += x;
        __syncthreads();
    }
    int run = lds[tdx] - s;
#pragma unroll
    for (int k = 0; k < 4; ++k) {
        int idx = tdx * 4 + k;
        if (idx < nb) { bkt_off[idx] = run; gcursor[idx] = run; }
        run += v[k];
    }
    if (tdx == 0) bkt_off[nb] = e;
}

// ---- place edges into buckets: bkt_edges[p] = (src<<7) | (dst & 127) ----
__global__ __launch_bounds__(256) void k_binB(const int* __restrict__ src,
                                              const int* __restrict__ dst, int e, int nb,
                                              int* __restrict__ gcursor,
                                              unsigned* __restrict__ bkt_edges) {
    __shared__ int lcnt[NBMAX];
    __shared__ int lbase[NBMAX];
    int tdx = threadIdx.x;
    for (int i = tdx; i < nb; i += 256) lcnt[i] = 0;
    __syncthreads();
    int base = blockIdx.x * (256 * EPT);
    unsigned val[EPT];
    int bkt[EPT];
#pragma unroll
    for (int k = 0; k < EPT; ++k) {
        int i = base + k * 256 + tdx;
        if (i < e) {
            int s_ = src[i], d_ = dst[i];
            val[k] = ((unsigned)s_ << BKT_SHIFT) | (unsigned)(d_ & (BKT_NODES - 1));
            bkt[k] = d_ >> BKT_SHIFT;
            atomicAdd(&lcnt[bkt[k]], 1);
        } else bkt[k] = -1;
    }
    __syncthreads();
    for (int b = tdx; b < nb; b += 256) {
        int c = lcnt[b];
        lbase[b] = c ? atomicAdd(&gcursor[b], c) : 0;
        lcnt[b] = 0;
    }
    __syncthreads();
#pragma unroll
    for (int k = 0; k < EPT; ++k) {
        if (bkt[k] >= 0) {
            int o = atomicAdd(&lcnt[bkt[k]], 1);
            bkt_edges[lbase[bkt[k]] + o] = val[k];
        }
    }
}

// ---- per-bucket counting sort -> per-node CSR + row_ptr + dis ----
__global__ __launch_bounds__(256) void k_bsort(
    const int* __restrict__ bkt_off, const unsigned* __restrict__ bkt_edges,
    int* __restrict__ row_ptr, int* __restrict__ csr_src, float* __restrict__ dis,
    int n, int e, int nb) {
    __shared__ int hist[BKT_NODES];
    __shared__ int sc[BKT_NODES];
    __shared__ int cur[BKT_NODES];
    int b = blockIdx.x, tdx = threadIdx.x;
    int beg = bkt_off[b], end = bkt_off[b + 1];
    if (tdx < BKT_NODES) hist[tdx] = 0;
    __syncthreads();
    for (int j = beg + tdx; j < end; j += 256)
        atomicAdd(&hist[bkt_edges[j] & (BKT_NODES - 1)], 1);
    __syncthreads();
    if (tdx < BKT_NODES) sc[tdx] = hist[tdx];
    __syncthreads();
    for (int off = 1; off < BKT_NODES; off <<= 1) {
        int v = (tdx < BKT_NODES && tdx >= off) ? sc[tdx - off] : 0;
        __syncthreads();
        if (tdx < BKT_NODES && tdx >= off) sc[tdx] += v;
        __syncthreads();
    }
    if (tdx < BKT_NODES) {
        int node = b * BKT_NODES + tdx;
        if (node < n) {
            int pos = beg + sc[tdx] - hist[tdx];   // exclusive prefix
            row_ptr[node] = pos;
            cur[tdx] = pos;
            dis[node] = rsqrtf((float)(hist[tdx] + 1));   // +1 self loop
        }
    }
    if (b == nb - 1 && tdx == 0) row_ptr[n] = e;
    __syncthreads();
    for (int j = beg + tdx; j < end; j += 256) {
        unsigned ev = bkt_edges[j];
        int p = atomicAdd(&cur[ev & (BKT_NODES - 1)], 1);
        csr_src[p] = (int)(ev >> BKT_SHIFT);
    }
}

// ---------------- matmul (t = dis * (x @ W)), row per thread ----------------
// acc[16] float4 = full 64-wide output row in VGPRs; W addresses are
// wave-uniform -> scalar-load/broadcast path; x row read as 16 float4.

#define FMA4(xs, w, a) \
    a.x = fmaf(xs, w.x, a.x); a.y = fmaf(xs, w.y, a.y); \
    a.z = fmaf(xs, w.z, a.z); a.w = fmaf(xs, w.w, a.w);

__global__ __launch_bounds__(256) void k_matmul64(
    const float* __restrict__ x, const float* __restrict__ W,
    const float* __restrict__ dis, float* __restrict__ t, int n) {
    int row = blockIdx.x * 256 + threadIdx.x;
    if (row >= n) return;
    const float4* __restrict__ xr = (const float4*)(x + (size_t)row * 64);
    const float4* __restrict__ W4 = (const float4*)W;
    float4 acc[16];
#pragma unroll
    for (int j = 0; j < 16; ++j) acc[j] = make_float4(0.f, 0.f, 0.f, 0.f);
    for (int kq = 0; kq < 16; ++kq) {         // k = 4*kq + {0,1,2,3}
        float4 xc = xr[kq];
        const float4* wr = W4 + kq * 64;      // 4 W-rows x 16 float4
#pragma unroll
        for (int j = 0; j < 16; ++j) { float4 w = wr[j];      FMA4(xc.x, w, acc[j]) }
#pragma unroll
        for (int j = 0; j < 16; ++j) { float4 w = wr[16 + j]; FMA4(xc.y, w, acc[j]) }
#pragma unroll
        for (int j = 0; j < 16; ++j) { float4 w = wr[32 + j]; FMA4(xc.z, w, acc[j]) }
#pragma unroll
        for (int j = 0; j < 16; ++j) { float4 w = wr[48 + j]; FMA4(xc.w, w, acc[j]) }
    }
    float dn = dis[row];
    float4* __restrict__ tr = (float4*)(t + (size_t)row * 64);
#pragma unroll
    for (int j = 0; j < 16; ++j) {
        float4 o;
        o.x = acc[j].x * dn; o.y = acc[j].y * dn;
        o.z = acc[j].z * dn; o.w = acc[j].w * dn;
        tr[j] = o;
    }
}

__global__ __launch_bounds__(256) void k_matmul16(
    const float* __restrict__ x, const float* __restrict__ W,
    const float* __restrict__ dis, float* __restrict__ t, int n) {
    int row = blockIdx.x * 256 + threadIdx.x;
    if (row >= n) return;
    const float4* __restrict__ xr = (const float4*)(x + (size_t)row * 64);
    const float4* __restrict__ W4 = (const float4*)W;   // W is [64][16]
    float4 acc[4];
#pragma unroll
    for (int j = 0; j < 4; ++j) acc[j] = make_float4(0.f, 0.f, 0.f, 0.f);
    for (int kq = 0; kq < 16; ++kq) {         // k = 4*kq + {0,1,2,3}
        float4 xc = xr[kq];
        const float4* wr = W4 + kq * 16;      // 4 W-rows x 4 float4
#pragma unroll
        for (int j = 0; j < 4; ++j) { float4 w = wr[j];      FMA4(xc.x, w, acc[j]) }
#pragma unroll
        for (int j = 0; j < 4; ++j) { float4 w = wr[4 + j];  FMA4(xc.y, w, acc[j]) }
#pragma unroll
        for (int j = 0; j < 4; ++j) { float4 w = wr[8 + j];  FMA4(xc.z, w, acc[j]) }
#pragma unroll
        for (int j = 0; j < 4; ++j) { float4 w = wr[12 + j]; FMA4(xc.w, w, acc[j]) }
    }
    float dn = dis[row];
    float4* __restrict__ tr = (float4*)(t + (size_t)row * 16);
#pragma unroll
    for (int j = 0; j < 4; ++j) {
        float4 o;
        o.x = acc[j].x * dn; o.y = acc[j].y * dn;
        o.z = acc[j].z * dn; o.w = acc[j].w * dn;
        tr[j] = o;
    }
}

// ---------------- gather (fused aggregate + finalize) ----------------
// one node per 16 lanes; lane holds float4. 2-edge unroll for ILP.
__global__ void k_gather64(const int* __restrict__ row_ptr, const int* __restrict__ csr_src,
                           const float* __restrict__ t, const float* __restrict__ dis,
                           const float* __restrict__ b, float* __restrict__ h, int n, int relu) {
    int tid  = blockIdx.x * blockDim.x + threadIdx.x;
    int node = tid >> 4;
    if (node >= n) return;
    int lane15  = threadIdx.x & 15;
    int grpbase = threadIdx.x & 48;
    int beg = row_ptr[node], end = row_ptr[node + 1];

    float4 acc = *(const float4*)(t + (size_t)node * 64 + lane15 * 4);   // self loop
    for (int j0 = beg; j0 < end; j0 += 16) {
        int myj = j0 + lane15;
        int sv  = (myj < end) ? csr_src[myj] : 0;
        int m   = end - j0; if (m > 16) m = 16;
        int k = 0;
        for (; k + 2 <= m; k += 2) {
            int s0 = __shfl(sv, grpbase + k);
            int s1 = __shfl(sv, grpbase + k + 1);
            const float4 v0 = *(const float4*)(t + (size_t)s0 * 64 + lane15 * 4);
            const float4 v1 = *(const float4*)(t + (size_t)s1 * 64 + lane15 * 4);
            acc.x += v0.x; acc.y += v0.y; acc.z += v0.z; acc.w += v0.w;
            acc.x += v1.x; acc.y += v1.y; acc.z += v1.z; acc.w += v1.w;
        }
        if (k < m) {
            int s0 = __shfl(sv, grpbase + k);
            const float4 v0 = *(const float4*)(t + (size_t)s0 * 64 + lane15 * 4);
            acc.x += v0.x; acc.y += v0.y; acc.z += v0.z; acc.w += v0.w;
        }
    }
    float dn = dis[node];
    const float4 bb = *(const float4*)(b + lane15 * 4);
    float4 o;
    o.x = fmaf(dn, acc.x, bb.x);
    o.y = fmaf(dn, acc.y, bb.y);
    o.z = fmaf(dn, acc.z, bb.z);
    o.w = fmaf(dn, acc.w, bb.w);
    if (relu) {
        o.x = fmaxf(o.x, 0.f); o.y = fmaxf(o.y, 0.f);
        o.z = fmaxf(o.z, 0.f); o.w = fmaxf(o.w, 0.f);
    }
    *(float4*)(h + (size_t)node * 64 + lane15 * 4) = o;
}

// one node per 4 lanes; lane holds float4 (4 of 16 features). No relu.
__global__ void k_gather16(const int* __restrict__ row_ptr, const int* __restrict__ csr_src,
                           const float* __restrict__ t, const float* __restrict__ dis,
                           const float* __restrict__ b, float* __restrict__ out, int n) {
    int tid  = blockIdx.x * blockDim.x + threadIdx.x;
    int node = tid >> 2;
    if (node >= n) return;
    int lane3   = threadIdx.x & 3;
    int grpbase = threadIdx.x & 60;
    int beg = row_ptr[node], end = row_ptr[node + 1];

    float4 acc = *(const float4*)(t + (size_t)node * 16 + lane3 * 4);    // self loop
    for (int j0 = beg; j0 < end; j0 += 4) {
        int myj = j0 + lane3;
        int sv  = (myj < end) ? csr_src[myj] : 0;
        int m   = end - j0; if (m > 4) m = 4;
        int k = 0;
        for (; k + 2 <= m; k += 2) {
            int s0 = __shfl(sv, grpbase + k);
            int s1 = __shfl(sv, grpbase + k + 1);
            const float4 v0 = *(const float4*)(t + (size_t)s0 * 16 + lane3 * 4);
            const float4 v1 = *(const float4*)(t + (size_t)s1 * 16 + lane3 * 4);
            acc.x += v0.x; acc.y += v0.y; acc.z += v0.z; acc.w += v0.w;
            acc.x += v1.x; acc.y += v1.y; acc.z += v1.z; acc.w += v1.w;
        }
        if (k < m) {
            int s0 = __shfl(sv, grpbase + k);
            const float4 v0 = *(const float4*)(t + (size_t)s0 * 16 + lane3 * 4);
            acc.x += v0.x; acc.y += v0.y; acc.z += v0.z; acc.w += v0.w;
        }
    }
    float dn = dis[node];
    const float4 bb = *(const float4*)(b + lane3 * 4);
    float4 o;
    o.x = fmaf(dn, acc.x, bb.x);
    o.y = fmaf(dn, acc.y, bb.y);
    o.z = fmaf(dn, acc.z, bb.z);
    o.w = fmaf(dn, acc.w, bb.w);
    *(float4*)(out + (size_t)node * 16 + lane3 * 4) = o;
}

// ---------------- launch ----------------

extern "C" void kernel_launch(void* const* d_in, const int* in_sizes, int n_in,
                              void* d_out, int out_size, void* d_ws, size_t ws_size,
                              hipStream_t stream) {
    const float* x     = (const float*)d_in[0];
    const int*   ei    = (const int*)d_in[1];
    const float* W_in  = (const float*)d_in[2];
    const float* b_in  = (const float*)d_in[3];
    const float* W_h   = (const float*)d_in[4];
    const float* b_h   = (const float*)d_in[5];
    const float* W_out = (const float*)d_in[6];
    const float* b_out = (const float*)d_in[7];

    const int n = in_sizes[0] / 64;
    const int e = in_sizes[1] / 2;
    const int* src = ei;
    const int* dst = ei + e;
    const int nb = (n + BKT_NODES - 1) / BKT_NODES;   // 782
    if (nb > NBMAX) return;

    char* ws = (char*)d_ws;
    size_t off = 0;
    auto alloc = [&](size_t bytes) { void* p = ws + off; off += (bytes + 255) & ~(size_t)255; return p; };
    float*    dis       = (float*)alloc((size_t)n * 4);
    float*    t         = (float*)alloc((size_t)n * 64 * 4);
    float*    h         = (float*)alloc((size_t)n * 64 * 4);
    int*      bcnt      = (int*)alloc((size_t)nb * 4);
    int*      bkt_off   = (int*)alloc(((size_t)nb + 1) * 4);
    int*      gcursor   = (int*)alloc((size_t)nb * 4);
    unsigned* bkt_edges = (unsigned*)alloc((size_t)e * 4);
    int*      row_ptr   = (int*)alloc(((size_t)n + 1) * 4);
    int*      csr_src   = (int*)alloc((size_t)e * 4);

    const int nblk_e = (e + 256 * EPT - 1) / (256 * EPT);
    const int nblk_n = (n + 255) / 256;

    // ---- CSR build (bucketed) ----
    hipMemsetAsync(bcnt, 0, (size_t)nb * 4, stream);
    k_bcount<<<nblk_e, 256, 0, stream>>>(dst, e, bcnt, nb);
    k_bscan <<<1, 256, 0, stream>>>(bcnt, bkt_off, gcursor, nb, e);
    k_binB  <<<nblk_e, 256, 0, stream>>>(src, dst, e, nb, gcursor, bkt_edges);
    k_bsort <<<nb, 256, 0, stream>>>(bkt_off, bkt_edges, row_ptr, csr_src, dis, n, e, nb);

    // ---- layer 1: x -> h ----
    k_matmul64<<<nblk_n, 256, 0, stream>>>(x, W_in, dis, t, n);
    k_gather64<<<(n * 16 + 255) / 256, 256, 0, stream>>>(row_ptr, csr_src, t, dis, b_in, h, n, 1);

    // ---- layers 2,3: h -> h ----
    for (int l = 0; l < 2; ++l) {
        k_matmul64<<<nblk_n, 256, 0, stream>>>(h, W_h + (size_t)l * 64 * 64, dis, t, n);
        k_gather64<<<(n * 16 + 255) / 256, 256, 0, stream>>>(row_ptr, csr_src, t, dis,
                                                             b_h + (size_t)l * 64, h, n, 1);
    }

    // ---- layer 4: h -> out (FOUT=16, no relu) ----
    k_matmul16<<<nblk_n, 256, 0, stream>>>(h, W_out, dis, t, n);
    k_gather16<<<(n * 4 + 255) / 256, 256, 0, stream>>>(row_ptr, csr_src, t, dis, b_out,
                                                        (float*)d_out, n);
}

// Round 6
// 318.107 us; speedup vs baseline: 8.2383x; 1.2018x over previous
//
#include <hip/hip_runtime.h>

// GCN: 4 layers (64->64->64->64->16), N=100k nodes, E=1.6M edges (+ self loops).
// out[i] = dis[i] * ( sum_{src->i} t[src] + t[i] ) + b,  t = dis * (h @ W)
// Round 6: t stored as bf16 (halves the gather's per-XCD L2 fill traffic,
// which round-5 counters showed is at its structural floor of ~8x |t|).
// Gather accumulates in f32; h and final output stay f32.

#define BKT_SHIFT 7
#define BKT_NODES 128
#define NBMAX 800               // max buckets (n <= 102400)
#define EPT 16                  // edges per thread in binning

// ---- bf16 helpers ----
__device__ __forceinline__ unsigned bf16rne(float f) {
    unsigned u = __float_as_uint(f);
    return (u + 0x7FFFu + ((u >> 16) & 1u)) >> 16;
}
__device__ __forceinline__ unsigned pack2(float a, float b) {
    return bf16rne(a) | (bf16rne(b) << 16);
}
__device__ __forceinline__ float lo16(unsigned u) { return __uint_as_float(u << 16); }
__device__ __forceinline__ float hi16(unsigned u) { return __uint_as_float(u & 0xFFFF0000u); }

// ---- bucket count: per-block LDS hist -> one global atomic per bucket ----
__global__ __launch_bounds__(256) void k_bcount(const int* __restrict__ dst, int e,
                                                int* __restrict__ bcnt, int nb) {
    __shared__ int l[NBMAX];
    int tdx = threadIdx.x;
    for (int i = tdx; i < nb; i += 256) l[i] = 0;
    __syncthreads();
    int base = blockIdx.x * (256 * EPT);
#pragma unroll
    for (int k = 0; k < EPT; ++k) {
        int i = base + k * 256 + tdx;
        if (i < e) atomicAdd(&l[dst[i] >> BKT_SHIFT], 1);
    }
    __syncthreads();
    for (int i = tdx; i < nb; i += 256) {
        int c = l[i];
        if (c) atomicAdd(&bcnt[i], c);
    }
}

// ---- single-block exclusive scan of nb (<=1024) bucket counts ----
__global__ void k_bscan(const int* __restrict__ bcnt, int* __restrict__ bkt_off,
                        int* __restrict__ gcursor, int nb, int e) {
    __shared__ int lds[256];
    int tdx = threadIdx.x;
    int v[4], s = 0;
#pragma unroll
    for (int k = 0; k < 4; ++k) { int idx = tdx * 4 + k; v[k] = (idx < nb) ? bcnt[idx] : 0; s += v[k]; }
    lds[tdx] = s;
    __syncthreads();
    for (int off = 1; off < 256; off <<= 1) {
        int x = (tdx >= off) ? lds[tdx - off] : 0;
        __syncthreads();
        if (tdx >= off) lds[tdx] += x;
        __syncthreads();
    }
    int run = lds[tdx] - s;
#pragma unroll
    for (int k = 0; k < 4; ++k) {
        int idx = tdx * 4 + k;
        if (idx < nb) { bkt_off[idx] = run; gcursor[idx] = run; }
        run += v[k];
    }
    if (tdx == 0) bkt_off[nb] = e;
}

// ---- place edges into buckets: bkt_edges[p] = (src<<7) | (dst & 127) ----
__global__ __launch_bounds__(256) void k_binB(const int* __restrict__ src,
                                              const int* __restrict__ dst, int e, int nb,
                                              int* __restrict__ gcursor,
                                              unsigned* __restrict__ bkt_edges) {
    __shared__ int lcnt[NBMAX];
    __shared__ int lbase[NBMAX];
    int tdx = threadIdx.x;
    for (int i = tdx; i < nb; i += 256) lcnt[i] = 0;
    __syncthreads();
    int base = blockIdx.x * (256 * EPT);
    unsigned val[EPT];
    int bkt[EPT];
#pragma unroll
    for (int k = 0; k < EPT; ++k) {
        int i = base + k * 256 + tdx;
        if (i < e) {
            int s_ = src[i], d_ = dst[i];
            val[k] = ((unsigned)s_ << BKT_SHIFT) | (unsigned)(d_ & (BKT_NODES - 1));
            bkt[k] = d_ >> BKT_SHIFT;
            atomicAdd(&lcnt[bkt[k]], 1);
        } else bkt[k] = -1;
    }
    __syncthreads();
    for (int b = tdx; b < nb; b += 256) {
        int c = lcnt[b];
        lbase[b] = c ? atomicAdd(&gcursor[b], c) : 0;
        lcnt[b] = 0;
    }
    __syncthreads();
#pragma unroll
    for (int k = 0; k < EPT; ++k) {
        if (bkt[k] >= 0) {
            int o = atomicAdd(&lcnt[bkt[k]], 1);
            bkt_edges[lbase[bkt[k]] + o] = val[k];
        }
    }
}

// ---- per-bucket counting sort -> per-node CSR + row_ptr + dis ----
__global__ __launch_bounds__(256) void k_bsort(
    const int* __restrict__ bkt_off, const unsigned* __restrict__ bkt_edges,
    int* __restrict__ row_ptr, int* __restrict__ csr_src, float* __restrict__ dis,
    int n, int e, int nb) {
    __shared__ int hist[BKT_NODES];
    __shared__ int sc[BKT_NODES];
    __shared__ int cur[BKT_NODES];
    int b = blockIdx.x, tdx = threadIdx.x;
    int beg = bkt_off[b], end = bkt_off[b + 1];
    if (tdx < BKT_NODES) hist[tdx] = 0;
    __syncthreads();
    for (int j = beg + tdx; j < end; j += 256)
        atomicAdd(&hist[bkt_edges[j] & (BKT_NODES - 1)], 1);
    __syncthreads();
    if (tdx < BKT_NODES) sc[tdx] = hist[tdx];
    __syncthreads();
    for (int off = 1; off < BKT_NODES; off <<= 1) {
        int v = (tdx < BKT_NODES && tdx >= off) ? sc[tdx - off] : 0;
        __syncthreads();
        if (tdx < BKT_NODES && tdx >= off) sc[tdx] += v;
        __syncthreads();
    }
    if (tdx < BKT_NODES) {
        int node = b * BKT_NODES + tdx;
        if (node < n) {
            int pos = beg + sc[tdx] - hist[tdx];   // exclusive prefix
            row_ptr[node] = pos;
            cur[tdx] = pos;
            dis[node] = rsqrtf((float)(hist[tdx] + 1));   // +1 self loop
        }
    }
    if (b == nb - 1 && tdx == 0) row_ptr[n] = e;
    __syncthreads();
    for (int j = beg + tdx; j < end; j += 256) {
        unsigned ev = bkt_edges[j];
        int p = atomicAdd(&cur[ev & (BKT_NODES - 1)], 1);
        csr_src[p] = (int)(ev >> BKT_SHIFT);
    }
}

// ---------------- matmul (t_bf16 = dis * (x @ W)), row per thread ----------------

#define FMA4(xs, w, a) \
    a.x = fmaf(xs, w.x, a.x); a.y = fmaf(xs, w.y, a.y); \
    a.z = fmaf(xs, w.z, a.z); a.w = fmaf(xs, w.w, a.w);

__global__ __launch_bounds__(256) void k_matmul64(
    const float* __restrict__ x, const float* __restrict__ W,
    const float* __restrict__ dis, unsigned* __restrict__ tb, int n) {
    int row = blockIdx.x * 256 + threadIdx.x;
    if (row >= n) return;
    const float4* __restrict__ xr = (const float4*)(x + (size_t)row * 64);
    const float4* __restrict__ W4 = (const float4*)W;
    float4 acc[16];
#pragma unroll
    for (int j = 0; j < 16; ++j) acc[j] = make_float4(0.f, 0.f, 0.f, 0.f);
    for (int kq = 0; kq < 16; ++kq) {         // k = 4*kq + {0,1,2,3}
        float4 xc = xr[kq];
        const float4* wr = W4 + kq * 64;      // 4 W-rows x 16 float4
#pragma unroll
        for (int j = 0; j < 16; ++j) { float4 w = wr[j];      FMA4(xc.x, w, acc[j]) }
#pragma unroll
        for (int j = 0; j < 16; ++j) { float4 w = wr[16 + j]; FMA4(xc.y, w, acc[j]) }
#pragma unroll
        for (int j = 0; j < 16; ++j) { float4 w = wr[32 + j]; FMA4(xc.z, w, acc[j]) }
#pragma unroll
        for (int j = 0; j < 16; ++j) { float4 w = wr[48 + j]; FMA4(xc.w, w, acc[j]) }
    }
    float dn = dis[row];
    uint4* __restrict__ tr = (uint4*)(tb + (size_t)row * 32);   // 64 bf16 = 32 uints
#pragma unroll
    for (int j = 0; j < 8; ++j) {
        float4 a0 = acc[2 * j], a1 = acc[2 * j + 1];
        uint4 o;
        o.x = pack2(a0.x * dn, a0.y * dn);
        o.y = pack2(a0.z * dn, a0.w * dn);
        o.z = pack2(a1.x * dn, a1.y * dn);
        o.w = pack2(a1.z * dn, a1.w * dn);
        tr[j] = o;
    }
}

__global__ __launch_bounds__(256) void k_matmul16(
    const float* __restrict__ x, const float* __restrict__ W,
    const float* __restrict__ dis, unsigned* __restrict__ tb, int n) {
    int row = blockIdx.x * 256 + threadIdx.x;
    if (row >= n) return;
    const float4* __restrict__ xr = (const float4*)(x + (size_t)row * 64);
    const float4* __restrict__ W4 = (const float4*)W;   // W is [64][16]
    float4 acc[4];
#pragma unroll
    for (int j = 0; j < 4; ++j) acc[j] = make_float4(0.f, 0.f, 0.f, 0.f);
    for (int kq = 0; kq < 16; ++kq) {
        float4 xc = xr[kq];
        const float4* wr = W4 + kq * 16;
#pragma unroll
        for (int j = 0; j < 4; ++j) { float4 w = wr[j];      FMA4(xc.x, w, acc[j]) }
#pragma unroll
        for (int j = 0; j < 4; ++j) { float4 w = wr[4 + j];  FMA4(xc.y, w, acc[j]) }
#pragma unroll
        for (int j = 0; j < 4; ++j) { float4 w = wr[8 + j];  FMA4(xc.z, w, acc[j]) }
#pragma unroll
        for (int j = 0; j < 4; ++j) { float4 w = wr[12 + j]; FMA4(xc.w, w, acc[j]) }
    }
    float dn = dis[row];
    uint4* __restrict__ tr = (uint4*)(tb + (size_t)row * 8);   // 16 bf16 = 8 uints
#pragma unroll
    for (int j = 0; j < 2; ++j) {
        float4 a0 = acc[2 * j], a1 = acc[2 * j + 1];
        uint4 o;
        o.x = pack2(a0.x * dn, a0.y * dn);
        o.y = pack2(a0.z * dn, a0.w * dn);
        o.z = pack2(a1.x * dn, a1.y * dn);
        o.w = pack2(a1.z * dn, a1.w * dn);
        tr[j] = o;
    }
}

// ---------------- gather (fused aggregate + finalize) ----------------
// one node per 16 lanes; lane holds 4 features (1 uint2 of bf16 per row read).
// 4-edge unroll for outstanding-load depth.
__global__ void k_gather64(const int* __restrict__ row_ptr, const int* __restrict__ csr_src,
                           const uint2* __restrict__ t2, const float* __restrict__ dis,
                           const float* __restrict__ b, float* __restrict__ h, int n, int relu) {
    int tid  = blockIdx.x * blockDim.x + threadIdx.x;
    int node = tid >> 4;
    if (node >= n) return;
    int lane15  = threadIdx.x & 15;
    int grpbase = threadIdx.x & 48;
    int beg = row_ptr[node], end = row_ptr[node + 1];

    uint2 sv0 = t2[(size_t)node * 16 + lane15];                // self loop
    float4 acc = make_float4(lo16(sv0.x), hi16(sv0.x), lo16(sv0.y), hi16(sv0.y));

    for (int j0 = beg; j0 < end; j0 += 16) {
        int myj = j0 + lane15;
        int sv  = (myj < end) ? csr_src[myj] : 0;
        int m   = end - j0; if (m > 16) m = 16;
        int k = 0;
        for (; k + 4 <= m; k += 4) {
            int s0 = __shfl(sv, grpbase + k);
            int s1 = __shfl(sv, grpbase + k + 1);
            int s2 = __shfl(sv, grpbase + k + 2);
            int s3 = __shfl(sv, grpbase + k + 3);
            uint2 v0 = t2[(size_t)s0 * 16 + lane15];
            uint2 v1 = t2[(size_t)s1 * 16 + lane15];
            uint2 v2 = t2[(size_t)s2 * 16 + lane15];
            uint2 v3 = t2[(size_t)s3 * 16 + lane15];
            acc.x += lo16(v0.x); acc.y += hi16(v0.x); acc.z += lo16(v0.y); acc.w += hi16(v0.y);
            acc.x += lo16(v1.x); acc.y += hi16(v1.x); acc.z += lo16(v1.y); acc.w += hi16(v1.y);
            acc.x += lo16(v2.x); acc.y += hi16(v2.x); acc.z += lo16(v2.y); acc.w += hi16(v2.y);
            acc.x += lo16(v3.x); acc.y += hi16(v3.x); acc.z += lo16(v3.y); acc.w += hi16(v3.y);
        }
        for (; k < m; ++k) {
            int s0 = __shfl(sv, grpbase + k);
            uint2 v0 = t2[(size_t)s0 * 16 + lane15];
            acc.x += lo16(v0.x); acc.y += hi16(v0.x); acc.z += lo16(v0.y); acc.w += hi16(v0.y);
        }
    }
    float dn = dis[node];
    const float4 bb = *(const float4*)(b + lane15 * 4);
    float4 o;
    o.x = fmaf(dn, acc.x, bb.x);
    o.y = fmaf(dn, acc.y, bb.y);
    o.z = fmaf(dn, acc.z, bb.z);
    o.w = fmaf(dn, acc.w, bb.w);
    if (relu) {
        o.x = fmaxf(o.x, 0.f); o.y = fmaxf(o.y, 0.f);
        o.z = fmaxf(o.z, 0.f); o.w = fmaxf(o.w, 0.f);
    }
    *(float4*)(h + (size_t)node * 64 + lane15 * 4) = o;
}

// one node per 4 lanes; lane holds 4 of 16 features. No relu.
__global__ void k_gather16(const int* __restrict__ row_ptr, const int* __restrict__ csr_src,
                           const uint2* __restrict__ t2, const float* __restrict__ dis,
                           const float* __restrict__ b, float* __restrict__ out, int n) {
    int tid  = blockIdx.x * blockDim.x + threadIdx.x;
    int node = tid >> 2;
    if (node >= n) return;
    int lane3   = threadIdx.x & 3;
    int grpbase = threadIdx.x & 60;
    int beg = row_ptr[node], end = row_ptr[node + 1];

    uint2 sv0 = t2[(size_t)node * 4 + lane3];                  // self loop
    float4 acc = make_float4(lo16(sv0.x), hi16(sv0.x), lo16(sv0.y), hi16(sv0.y));

    for (int j0 = beg; j0 < end; j0 += 4) {
        int myj = j0 + lane3;
        int sv  = (myj < end) ? csr_src[myj] : 0;
        int m   = end - j0; if (m > 4) m = 4;
        int k = 0;
        for (; k + 2 <= m; k += 2) {
            int s0 = __shfl(sv, grpbase + k);
            int s1 = __shfl(sv, grpbase + k + 1);
            uint2 v0 = t2[(size_t)s0 * 4 + lane3];
            uint2 v1 = t2[(size_t)s1 * 4 + lane3];
            acc.x += lo16(v0.x); acc.y += hi16(v0.x); acc.z += lo16(v0.y); acc.w += hi16(v0.y);
            acc.x += lo16(v1.x); acc.y += hi16(v1.x); acc.z += lo16(v1.y); acc.w += hi16(v1.y);
        }
        for (; k < m; ++k) {
            int s0 = __shfl(sv, grpbase + k);
            uint2 v0 = t2[(size_t)s0 * 4 + lane3];
            acc.x += lo16(v0.x); acc.y += hi16(v0.x); acc.z += lo16(v0.y); acc.w += hi16(v0.y);
        }
    }
    float dn = dis[node];
    const float4 bb = *(const float4*)(b + lane3 * 4);
    float4 o;
    o.x = fmaf(dn, acc.x, bb.x);
    o.y = fmaf(dn, acc.y, bb.y);
    o.z = fmaf(dn, acc.z, bb.z);
    o.w = fmaf(dn, acc.w, bb.w);
    *(float4*)(out + (size_t)node * 16 + lane3 * 4) = o;
}

// ---------------- launch ----------------

extern "C" void kernel_launch(void* const* d_in, const int* in_sizes, int n_in,
                              void* d_out, int out_size, void* d_ws, size_t ws_size,
                              hipStream_t stream) {
    const float* x     = (const float*)d_in[0];
    const int*   ei    = (const int*)d_in[1];
    const float* W_in  = (const float*)d_in[2];
    const float* b_in  = (const float*)d_in[3];
    const float* W_h   = (const float*)d_in[4];
    const float* b_h   = (const float*)d_in[5];
    const float* W_out = (const float*)d_in[6];
    const float* b_out = (const float*)d_in[7];

    const int n = in_sizes[0] / 64;
    const int e = in_sizes[1] / 2;
    const int* src = ei;
    const int* dst = ei + e;
    const int nb = (n + BKT_NODES - 1) / BKT_NODES;   // 782
    if (nb > NBMAX) return;

    char* ws = (char*)d_ws;
    size_t off = 0;
    auto alloc = [&](size_t bytes) { void* p = ws + off; off += (bytes + 255) & ~(size_t)255; return p; };
    float*    dis       = (float*)alloc((size_t)n * 4);
    unsigned* tb        = (unsigned*)alloc((size_t)n * 64 * 2);   // bf16 t (also reused at 16-wide)
    float*    h         = (float*)alloc((size_t)n * 64 * 4);
    int*      bcnt      = (int*)alloc((size_t)nb * 4);
    int*      bkt_off   = (int*)alloc(((size_t)nb + 1) * 4);
    int*      gcursor   = (int*)alloc((size_t)nb * 4);
    unsigned* bkt_edges = (unsigned*)alloc((size_t)e * 4);
    int*      row_ptr   = (int*)alloc(((size_t)n + 1) * 4);
    int*      csr_src   = (int*)alloc((size_t)e * 4);

    const int nblk_e = (e + 256 * EPT - 1) / (256 * EPT);
    const int nblk_n = (n + 255) / 256;

    // ---- CSR build (bucketed) ----
    hipMemsetAsync(bcnt, 0, (size_t)nb * 4, stream);
    k_bcount<<<nblk_e, 256, 0, stream>>>(dst, e, bcnt, nb);
    k_bscan <<<1, 256, 0, stream>>>(bcnt, bkt_off, gcursor, nb, e);
    k_binB  <<<nblk_e, 256, 0, stream>>>(src, dst, e, nb, gcursor, bkt_edges);
    k_bsort <<<nb, 256, 0, stream>>>(bkt_off, bkt_edges, row_ptr, csr_src, dis, n, e, nb);

    // ---- layer 1: x -> h ----
    k_matmul64<<<nblk_n, 256, 0, stream>>>(x, W_in, dis, tb, n);
    k_gather64<<<(n * 16 + 255) / 256, 256, 0, stream>>>(row_ptr, csr_src, (const uint2*)tb,
                                                         dis, b_in, h, n, 1);

    // ---- layers 2,3: h -> h ----
    for (int l = 0; l < 2; ++l) {
        k_matmul64<<<nblk_n, 256, 0, stream>>>(h, W_h + (size_t)l * 64 * 64, dis, tb, n);
        k_gather64<<<(n * 16 + 255) / 256, 256, 0, stream>>>(row_ptr, csr_src, (const uint2*)tb,
                                                             dis, b_h + (size_t)l * 64, h, n, 1);
    }

    // ---- layer 4: h -> out (FOUT=16, no relu) ----
    k_matmul16<<<nblk_n, 256, 0, stream>>>(h, W_out, dis, tb, n);
    k_gather16<<<(n * 4 + 255) / 256, 256, 0, stream>>>(row_ptr, csr_src, (const uint2*)tb,
                                                        dis, b_out, (float*)d_out, n);
}